// Round 1
// baseline (329.006 us; speedup 1.0000x reference)
//
#include <hip/hip_runtime.h>
#include <math.h>

#define NN 750
#define SN 1024
#define THR 0.01f

__device__ __forceinline__ float bn_inv() { return 1.0f / sqrtf(1.0f + 1e-5f); }

// ---------------- linear1 + BN + ReLU -> X0[b][0..250) ----------------
__global__ __launch_bounds__(256) void k_lin1(
    const float* __restrict__ xs, const float* __restrict__ W1,
    const float* __restrict__ b1, const float* __restrict__ gl,
    const float* __restrict__ bl, float* __restrict__ X0)
{
  int b = blockIdx.x, t = threadIdx.x;
  __shared__ float xsh[250];
  for (int k = t; k < 250; k += 256) xsh[k] = xs[b * 250 + k];
  __syncthreads();
  if (t < 250) {
    float acc = 0.f;
    #pragma unroll 10
    for (int k = 0; k < 250; ++k) acc = fmaf(xsh[k], W1[k * 250 + t], acc);
    float v = (acc + b1[t]) * bn_inv() * gl[t] + bl[t];
    X0[b * 1000 + t] = fmaxf(v, 0.f);
  }
}

// ------- GCN block: sort-by-d + exact range search + prefix sums -------
__global__ __launch_bounds__(256) void k_graph(
    const float* __restrict__ xg, const float* __restrict__ Wg,
    const float* __restrict__ bgp, const float* __restrict__ g1p,
    const float* __restrict__ be1p, float* __restrict__ X0)
{
  int b = blockIdx.x, tid = threadIdx.x;
  __shared__ float key[SN];
  __shared__ int   idxs[SN];
  __shared__ float dns[NN];
  __shared__ unsigned short los[NN], his[NN];
  __shared__ float4 zb[2][NN * 2];
  __shared__ float wgs[64], bgs[8];

  for (int i = tid; i < SN; i += 256) {
    if (i < NN) { key[i] = xg[(b * NN + i) * 8]; idxs[i] = i; }
    else        { key[i] = 3.4e38f; idxs[i] = -1; }
  }
  if (tid < 64) wgs[tid] = Wg[tid];
  if (tid < 8)  bgs[tid] = bgp[tid];
  __syncthreads();

  // bitonic sort ascending on (key, idx), padded to 1024
  for (int k = 2; k <= SN; k <<= 1) {
    for (int j = k >> 1; j > 0; j >>= 1) {
      for (int i = tid; i < SN; i += 256) {
        int ixj = i ^ j;
        if (ixj > i) {
          float a = key[i], c = key[ixj];
          bool up = ((i & k) == 0);
          if (up ? (a > c) : (a < c)) {
            key[i] = c; key[ixj] = a;
            int ta = idxs[i]; idxs[i] = idxs[ixj]; idxs[ixj] = ta;
          }
        }
      }
      __syncthreads();
    }
  }

  // exact neighbor ranges + D^{-1/2}; predicate identical to reference
  for (int p = tid; p < NN; p += 256) {
    float dp = key[p];
    int a = 0, bq = p;                 // first q<=p with pred true
    while (a < bq) { int m = (a + bq) >> 1; float df = dp - key[m];
      if (df * df < THR) bq = m; else a = m + 1; }
    int lo = a;
    a = p + 1; bq = NN;                // first q>p with pred false
    while (a < bq) { int m = (a + bq) >> 1; float df = dp - key[m];
      if (df * df < THR) a = m + 1; else bq = m; }
    int hi = a;
    los[p] = (unsigned short)lo; his[p] = (unsigned short)hi;
    dns[p] = 1.0f / sqrtf((float)(hi - lo));
  }
  __syncthreads();

  // z[p][f] = dn_p * (x_graph[j] @ Wg)[f], sorted order
  for (int p = tid; p < NN; p += 256) {
    int j = idxs[p];
    const float4* xp = (const float4*)(xg + (size_t)(b * NN + j) * 8);
    float4 x0 = xp[0], x1 = xp[1];
    float xv[8] = {x0.x, x0.y, x0.z, x0.w, x1.x, x1.y, x1.z, x1.w};
    float dn = dns[p];
    float zf[8];
    #pragma unroll
    for (int f = 0; f < 8; ++f) {
      float acc = 0.f;
      #pragma unroll
      for (int k = 0; k < 8; ++k) acc = fmaf(xv[k], wgs[k * 8 + f], acc);
      zf[f] = dn * acc;
    }
    zb[0][p * 2]     = make_float4(zf[0], zf[1], zf[2], zf[3]);
    zb[0][p * 2 + 1] = make_float4(zf[4], zf[5], zf[6], zf[7]);
  }
  __syncthreads();

  // inclusive prefix sum over p (Hillis-Steele, ping-pong)
  int srcb = 0;
  for (int st = 1; st < NN; st <<= 1) {
    int dstb = srcb ^ 1;
    for (int e = tid; e < NN * 2; e += 256) {
      int p = e >> 1, h = e & 1;
      float4 v = zb[srcb][e];
      if (p >= st) {
        float4 u = zb[srcb][(p - st) * 2 + h];
        v.x += u.x; v.y += u.y; v.z += u.z; v.w += u.w;
      }
      zb[dstb][e] = v;
    }
    __syncthreads();
    srcb = dstb;
  }

  float g1v = g1p[0], be1v = be1p[0], inv = bn_inv();
  for (int p = tid; p < NN; p += 256) {
    int lo = los[p], hi = his[p];
    float4 aA = zb[srcb][(hi - 1) * 2], aB = zb[srcb][(hi - 1) * 2 + 1];
    if (lo > 0) {
      float4 sA = zb[srcb][(lo - 1) * 2], sB = zb[srcb][(lo - 1) * 2 + 1];
      aA.x -= sA.x; aA.y -= sA.y; aA.z -= sA.z; aA.w -= sA.w;
      aB.x -= sB.x; aB.y -= sB.y; aB.z -= sB.z; aB.w -= sB.w;
    }
    float dn = dns[p];
    float S[8] = {aA.x, aA.y, aA.z, aA.w, aB.x, aB.y, aB.z, aB.w};
    float gsum = 0.f;
    #pragma unroll
    for (int f = 0; f < 8; ++f) {
      float h = dn * S[f] + bgs[f];
      float v = h * inv * g1v + be1v;
      gsum += fmaxf(v, 0.f);
    }
    X0[b * 1000 + 250 + idxs[p]] = gsum * 0.125f;
  }
}

// ---------------- conv1 (1->32,k5,pad2) + BN + ReLU + pool2 ----------------
__global__ __launch_bounds__(256) void k_conv1(
    const float* __restrict__ X0, const float* __restrict__ Wc1,
    const float* __restrict__ bc1, const float* __restrict__ gc1,
    const float* __restrict__ bec1, float* __restrict__ Y1)
{
  int b = blockIdx.x, p0 = blockIdx.y * 125, tid = threadIdx.x;
  __shared__ float xsh[254];
  __shared__ float w[160], bb[32], gg[32], ee[32];
  for (int i = tid; i < 254; i += 256) {
    int gq = 2 * p0 - 2 + i;
    xsh[i] = (gq >= 0 && gq < 1000) ? X0[b * 1000 + gq] : 0.f;
  }
  for (int i = tid; i < 160; i += 256) w[i] = Wc1[i];
  if (tid < 32) { bb[tid] = bc1[tid]; gg[tid] = gc1[tid]; ee[tid] = bec1[tid]; }
  __syncthreads();
  float inv = bn_inv();
  for (int o = tid; o < 32 * 125; o += 256) {
    int c = o / 125, pl = o % 125;
    int base = 2 * pl;
    float v0 = 0.f, v1 = 0.f;
    #pragma unroll
    for (int k = 0; k < 5; ++k) {
      float wk = w[c * 5 + k];
      v0 = fmaf(xsh[base + k], wk, v0);
      v1 = fmaf(xsh[base + 1 + k], wk, v1);
    }
    float s0 = fmaxf((v0 + bb[c]) * inv * gg[c] + ee[c], 0.f);
    float s1 = fmaxf((v1 + bb[c]) * inv * gg[c] + ee[c], 0.f);
    Y1[((b * 32) + c) * 500 + p0 + pl] = fmaxf(s0, s1);
  }
}

// ---------------- conv2 (32->64,k5,pad2) + BN + ReLU + pool2 ----------------
__global__ __launch_bounds__(256) void k_conv2(
    const float* __restrict__ Y1, const float* __restrict__ Wc2,
    const float* __restrict__ bc2, const float* __restrict__ gc2,
    const float* __restrict__ bec2, float* __restrict__ Y2)
{
  int b = blockIdx.x, p0 = blockIdx.y * 52, tid = threadIdx.x;
  __shared__ float xin[32][108];
  __shared__ float ws2[64 * 161];     // row stride 161 kills 16-way bank conflict
  for (int e = tid; e < 32 * 108; e += 256) {
    int ci = e / 108, li = e % 108;
    int gq = 2 * p0 - 2 + li;
    xin[ci][li] = (gq >= 0 && gq < 500) ? Y1[((b * 32) + ci) * 500 + gq] : 0.f;
  }
  for (int e = tid; e < 64 * 160; e += 256) {
    int co = e / 160, r = e % 160;
    ws2[co * 161 + r] = Wc2[e];
  }
  __syncthreads();
  int co = tid >> 2, sub = tid & 3;
  int base = sub * 26;
  float acc[26];
  #pragma unroll
  for (int r = 0; r < 26; ++r) acc[r] = 0.f;
  for (int ci = 0; ci < 32; ++ci) {
    float xr[30];
    #pragma unroll
    for (int jj = 0; jj < 30; ++jj) xr[jj] = xin[ci][base + jj];
    #pragma unroll
    for (int k = 0; k < 5; ++k) {
      float wk = ws2[co * 161 + ci * 5 + k];
      #pragma unroll
      for (int r = 0; r < 26; ++r) acc[r] = fmaf(xr[r + k], wk, acc[r]);
    }
  }
  float inv = bn_inv();
  float bc = bc2[co], gc = gc2[co], ec = bec2[co];
  int ps = p0 + sub * 13;
  #pragma unroll
  for (int r = 0; r < 13; ++r) {
    int p = ps + r;
    if (p < 250) {
      float a0 = fmaxf((acc[2 * r] + bc) * inv * gc + ec, 0.f);
      float a1 = fmaxf((acc[2 * r + 1] + bc) * inv * gc + ec, 0.f);
      Y2[((b * 64) + co) * 250 + p] = fmaxf(a0, a1);
    }
  }
}

// ------- conv3 as split-K GEMM: M=64(b) N=128(o) K=16000, partials -------
__global__ __launch_bounds__(256) void k_conv3(
    const float* __restrict__ Y2, const float* __restrict__ Wc3,
    float* __restrict__ C3P, int CP)
{
  int pb = blockIdx.x, tid = threadIdx.x;
  __shared__ float As[64 * 64];        // [b][k]
  __shared__ float Bs[64 * 128];       // [k][o], o-slot XOR-swizzled by k
  int bt = tid >> 5, ot = tid & 31;
  int b0 = bt * 8, o0 = ot * 4;
  float4 acc[8];
  #pragma unroll
  for (int r = 0; r < 8; ++r) acc[r] = make_float4(0.f, 0.f, 0.f, 0.f);

  for (int s = 0; s < CP; ++s) {
    int kbase = (pb * CP + s) * 64;
    __syncthreads();
    for (int e = tid; e < 4096; e += 256) {       // A stage, coalesced, linear
      int bb = e >> 6, kk = e & 63;
      As[e] = Y2[bb * 16000 + kbase + kk];
    }
    for (int e = tid; e < 8192; e += 256) {       // B stage, swizzled dest
      int o = e >> 6, kk = e & 63;
      float v = Wc3[o * 16000 + kbase + kk];
      Bs[kk * 128 + ((((o >> 2) ^ (kk & 31)) << 2) | (o & 3))] = v;
    }
    __syncthreads();
    for (int ks = 0; ks < 64; ks += 4) {
      float4 av[8];
      #pragma unroll
      for (int r = 0; r < 8; ++r)
        av[r] = *(const float4*)&As[(b0 + r) * 64 + ks];
      float4 bv[4];
      #pragma unroll
      for (int q = 0; q < 4; ++q) {
        int kk = ks + q;
        bv[q] = *(const float4*)&Bs[kk * 128 + ((ot ^ (kk & 31)) << 2)];
      }
      #pragma unroll
      for (int q = 0; q < 4; ++q) {
        #pragma unroll
        for (int r = 0; r < 8; ++r) {
          float a = (q == 0) ? av[r].x : (q == 1) ? av[r].y
                  : (q == 2) ? av[r].z : av[r].w;
          acc[r].x = fmaf(a, bv[q].x, acc[r].x);
          acc[r].y = fmaf(a, bv[q].y, acc[r].y);
          acc[r].z = fmaf(a, bv[q].z, acc[r].z);
          acc[r].w = fmaf(a, bv[q].w, acc[r].w);
        }
      }
    }
  }
  #pragma unroll
  for (int r = 0; r < 8; ++r)
    *(float4*)&C3P[(size_t)pb * 8192 + (b0 + r) * 128 + o0] = acc[r];
}

// ------- reduce split-K partials + bc3, fc1+BN+ReLU, fc2, log_softmax -------
__global__ __launch_bounds__(64) void k_fc(
    const float* __restrict__ C3P, const float* __restrict__ bc3,
    const float* __restrict__ Wf, const float* __restrict__ bf,
    const float* __restrict__ gf, const float* __restrict__ bef,
    const float* __restrict__ Wo, const float* __restrict__ bo,
    float* __restrict__ out, int NB)
{
  int b = blockIdx.x, t = threadIdx.x;
  __shared__ float z[128];
  __shared__ float f[64];
  for (int o = t; o < 128; o += 64) {
    float acc = bc3[o];
    for (int c = 0; c < NB; ++c) acc += C3P[(size_t)c * 8192 + b * 128 + o];
    z[o] = acc;
  }
  __syncthreads();
  float inv = bn_inv();
  {
    float acc = 0.f;
    #pragma unroll 8
    for (int k = 0; k < 128; ++k) acc = fmaf(z[k], Wf[k * 64 + t], acc);
    float v = (acc + bf[t]) * inv * gf[t] + bef[t];
    f[t] = fmaxf(v, 0.f);
  }
  __syncthreads();
  float logit = 0.f;
  if (t < 12) {
    float acc = 0.f;
    #pragma unroll 8
    for (int k = 0; k < 64; ++k) acc = fmaf(f[k], Wo[k * 12 + t], acc);
    logit = acc + bo[t];
  }
  float m = (t < 12) ? logit : -3.4e38f;
  for (int off = 32; off > 0; off >>= 1) m = fmaxf(m, __shfl_xor(m, off));
  float e = (t < 12) ? expf(logit - m) : 0.f;
  float ssum = e;
  for (int off = 32; off > 0; off >>= 1) ssum += __shfl_xor(ssum, off);
  if (t < 12) out[b * 12 + t] = logit - m - logf(ssum);
}

extern "C" void kernel_launch(void* const* d_in, const int* in_sizes, int n_in,
                              void* d_out, int out_size, void* d_ws, size_t ws_size,
                              hipStream_t stream)
{
  const float* xs   = (const float*)d_in[0];
  const float* xg   = (const float*)d_in[1];
  const float* W1   = (const float*)d_in[2];
  const float* b1   = (const float*)d_in[3];
  const float* gl   = (const float*)d_in[4];
  const float* bl   = (const float*)d_in[5];
  const float* Wg   = (const float*)d_in[6];
  const float* bg   = (const float*)d_in[7];
  const float* g1   = (const float*)d_in[8];
  const float* be1  = (const float*)d_in[9];
  const float* Wc1  = (const float*)d_in[10];
  const float* bc1  = (const float*)d_in[11];
  const float* gc1  = (const float*)d_in[12];
  const float* bec1 = (const float*)d_in[13];
  const float* Wc2  = (const float*)d_in[14];
  const float* bc2  = (const float*)d_in[15];
  const float* gc2  = (const float*)d_in[16];
  const float* bec2 = (const float*)d_in[17];
  const float* Wc3  = (const float*)d_in[18];
  const float* bc3  = (const float*)d_in[19];
  const float* Wf   = (const float*)d_in[20];
  const float* bfp  = (const float*)d_in[21];
  const float* gf   = (const float*)d_in[22];
  const float* bef  = (const float*)d_in[23];
  const float* Wo   = (const float*)d_in[24];
  const float* bo   = (const float*)d_in[25];
  float* out = (float*)d_out;

  float* W   = (float*)d_ws;
  float* X0  = W;                 // 64000 floats
  float* Y1  = W + 64000;         // 1,024,000
  float* Y2  = W + 1088000;       // 1,024,000
  float* C3P = W + 2112000;       // NB*8192

  long availl = (long)(ws_size / 4) - 2112000L;
  const int cand[8] = {250, 125, 50, 25, 10, 5, 2, 1};
  int NB = 1;
  for (int i = 0; i < 8; ++i)
    if ((long)cand[i] * 8192L <= availl) { NB = cand[i]; break; }
  int CP = 250 / NB;

  k_lin1 <<<64, 256, 0, stream>>>(xs, W1, b1, gl, bl, X0);
  k_graph<<<64, 256, 0, stream>>>(xg, Wg, bg, g1, be1, X0);
  k_conv1<<<dim3(64, 4), 256, 0, stream>>>(X0, Wc1, bc1, gc1, bec1, Y1);
  k_conv2<<<dim3(64, 5), 256, 0, stream>>>(Y1, Wc2, bc2, gc2, bec2, Y2);
  k_conv3<<<NB, 256, 0, stream>>>(Y2, Wc3, C3P, CP);
  k_fc   <<<64, 64, 0, stream>>>(C3P, bc3, Wf, bfp, gf, bef, Wo, bo, out, NB);
}

// Round 2
// 222.547 us; speedup vs baseline: 1.4784x; 1.4784x over previous
//
#include <hip/hip_runtime.h>
#include <math.h>

#define NN 750
#define SN 1024
#define THR 0.01f

__device__ __forceinline__ float bn_inv() { return 1.0f / sqrtf(1.0f + 1e-5f); }

// ---------------- linear1 + BN + ReLU -> X0[b][0..250) ----------------
__global__ __launch_bounds__(256) void k_lin1(
    const float* __restrict__ xs, const float* __restrict__ W1,
    const float* __restrict__ b1, const float* __restrict__ gl,
    const float* __restrict__ bl, float* __restrict__ X0)
{
  int b = blockIdx.x, t = threadIdx.x;
  __shared__ float xsh[250];
  for (int k = t; k < 250; k += 256) xsh[k] = xs[b * 250 + k];
  __syncthreads();
  if (t < 250) {
    float acc = 0.f;
    #pragma unroll 10
    for (int k = 0; k < 250; ++k) acc = fmaf(xsh[k], W1[k * 250 + t], acc);
    float v = (acc + b1[t]) * bn_inv() * gl[t] + bl[t];
    X0[b * 1000 + t] = fmaxf(v, 0.f);
  }
}

// ------- GCN block: sort-by-d + exact range search + prefix sums -------
__global__ __launch_bounds__(256) void k_graph(
    const float* __restrict__ xg, const float* __restrict__ Wg,
    const float* __restrict__ bgp, const float* __restrict__ g1p,
    const float* __restrict__ be1p, float* __restrict__ X0)
{
  int b = blockIdx.x, tid = threadIdx.x;
  __shared__ float key[SN];
  __shared__ int   idxs[SN];
  __shared__ float dns[NN];
  __shared__ unsigned short los[NN], his[NN];
  __shared__ float4 zb[2][NN * 2];
  __shared__ float wgs[64], bgs[8];

  for (int i = tid; i < SN; i += 256) {
    if (i < NN) { key[i] = xg[(b * NN + i) * 8]; idxs[i] = i; }
    else        { key[i] = 3.4e38f; idxs[i] = -1; }
  }
  if (tid < 64) wgs[tid] = Wg[tid];
  if (tid < 8)  bgs[tid] = bgp[tid];
  __syncthreads();

  // bitonic sort ascending on (key, idx), padded to 1024
  for (int k = 2; k <= SN; k <<= 1) {
    for (int j = k >> 1; j > 0; j >>= 1) {
      for (int i = tid; i < SN; i += 256) {
        int ixj = i ^ j;
        if (ixj > i) {
          float a = key[i], c = key[ixj];
          bool up = ((i & k) == 0);
          if (up ? (a > c) : (a < c)) {
            key[i] = c; key[ixj] = a;
            int ta = idxs[i]; idxs[i] = idxs[ixj]; idxs[ixj] = ta;
          }
        }
      }
      __syncthreads();
    }
  }

  // exact neighbor ranges + D^{-1/2}; predicate identical to reference
  for (int p = tid; p < NN; p += 256) {
    float dp = key[p];
    int a = 0, bq = p;                 // first q<=p with pred true
    while (a < bq) { int m = (a + bq) >> 1; float df = dp - key[m];
      if (df * df < THR) bq = m; else a = m + 1; }
    int lo = a;
    a = p + 1; bq = NN;                // first q>p with pred false
    while (a < bq) { int m = (a + bq) >> 1; float df = dp - key[m];
      if (df * df < THR) a = m + 1; else bq = m; }
    int hi = a;
    los[p] = (unsigned short)lo; his[p] = (unsigned short)hi;
    dns[p] = 1.0f / sqrtf((float)(hi - lo));
  }
  __syncthreads();

  // z[p][f] = dn_p * (x_graph[j] @ Wg)[f], sorted order
  for (int p = tid; p < NN; p += 256) {
    int j = idxs[p];
    const float4* xp = (const float4*)(xg + (size_t)(b * NN + j) * 8);
    float4 x0 = xp[0], x1 = xp[1];
    float xv[8] = {x0.x, x0.y, x0.z, x0.w, x1.x, x1.y, x1.z, x1.w};
    float dn = dns[p];
    float zf[8];
    #pragma unroll
    for (int f = 0; f < 8; ++f) {
      float acc = 0.f;
      #pragma unroll
      for (int k = 0; k < 8; ++k) acc = fmaf(xv[k], wgs[k * 8 + f], acc);
      zf[f] = dn * acc;
    }
    zb[0][p * 2]     = make_float4(zf[0], zf[1], zf[2], zf[3]);
    zb[0][p * 2 + 1] = make_float4(zf[4], zf[5], zf[6], zf[7]);
  }
  __syncthreads();

  // inclusive prefix sum over p (Hillis-Steele, ping-pong)
  int srcb = 0;
  for (int st = 1; st < NN; st <<= 1) {
    int dstb = srcb ^ 1;
    for (int e = tid; e < NN * 2; e += 256) {
      int p = e >> 1, h = e & 1;
      float4 v = zb[srcb][e];
      if (p >= st) {
        float4 u = zb[srcb][(p - st) * 2 + h];
        v.x += u.x; v.y += u.y; v.z += u.z; v.w += u.w;
      }
      zb[dstb][e] = v;
    }
    __syncthreads();
    srcb = dstb;
  }

  float g1v = g1p[0], be1v = be1p[0], inv = bn_inv();
  for (int p = tid; p < NN; p += 256) {
    int lo = los[p], hi = his[p];
    float4 aA = zb[srcb][(hi - 1) * 2], aB = zb[srcb][(hi - 1) * 2 + 1];
    if (lo > 0) {
      float4 sA = zb[srcb][(lo - 1) * 2], sB = zb[srcb][(lo - 1) * 2 + 1];
      aA.x -= sA.x; aA.y -= sA.y; aA.z -= sA.z; aA.w -= sA.w;
      aB.x -= sB.x; aB.y -= sB.y; aB.z -= sB.z; aB.w -= sB.w;
    }
    float dn = dns[p];
    float S[8] = {aA.x, aA.y, aA.z, aA.w, aB.x, aB.y, aB.z, aB.w};
    float gsum = 0.f;
    #pragma unroll
    for (int f = 0; f < 8; ++f) {
      float h = dn * S[f] + bgs[f];
      float v = h * inv * g1v + be1v;
      gsum += fmaxf(v, 0.f);
    }
    X0[b * 1000 + 250 + idxs[p]] = gsum * 0.125f;
  }
}

// ---------------- conv1 (1->32,k5,pad2) + BN + ReLU + pool2 ----------------
__global__ __launch_bounds__(256) void k_conv1(
    const float* __restrict__ X0, const float* __restrict__ Wc1,
    const float* __restrict__ bc1, const float* __restrict__ gc1,
    const float* __restrict__ bec1, float* __restrict__ Y1)
{
  int b = blockIdx.x, p0 = blockIdx.y * 125, tid = threadIdx.x;
  __shared__ float xsh[254];
  __shared__ float w[160], bb[32], gg[32], ee[32];
  for (int i = tid; i < 254; i += 256) {
    int gq = 2 * p0 - 2 + i;
    xsh[i] = (gq >= 0 && gq < 1000) ? X0[b * 1000 + gq] : 0.f;
  }
  for (int i = tid; i < 160; i += 256) w[i] = Wc1[i];
  if (tid < 32) { bb[tid] = bc1[tid]; gg[tid] = gc1[tid]; ee[tid] = bec1[tid]; }
  __syncthreads();
  float inv = bn_inv();
  for (int o = tid; o < 32 * 125; o += 256) {
    int c = o / 125, pl = o % 125;
    int base = 2 * pl;
    float v0 = 0.f, v1 = 0.f;
    #pragma unroll
    for (int k = 0; k < 5; ++k) {
      float wk = w[c * 5 + k];
      v0 = fmaf(xsh[base + k], wk, v0);
      v1 = fmaf(xsh[base + 1 + k], wk, v1);
    }
    float s0 = fmaxf((v0 + bb[c]) * inv * gg[c] + ee[c], 0.f);
    float s1 = fmaxf((v1 + bb[c]) * inv * gg[c] + ee[c], 0.f);
    Y1[((b * 32) + c) * 500 + p0 + pl] = fmaxf(s0, s1);
  }
}

// ---------------- conv2 (32->64,k5,pad2) + BN + ReLU + pool2 ----------------
__global__ __launch_bounds__(256) void k_conv2(
    const float* __restrict__ Y1, const float* __restrict__ Wc2,
    const float* __restrict__ bc2, const float* __restrict__ gc2,
    const float* __restrict__ bec2, float* __restrict__ Y2)
{
  int b = blockIdx.x, p0 = blockIdx.y * 52, tid = threadIdx.x;
  __shared__ float xin[32][108];
  __shared__ float ws2[64 * 161];     // row stride 161 kills 16-way bank conflict
  for (int e = tid; e < 32 * 108; e += 256) {
    int ci = e / 108, li = e % 108;
    int gq = 2 * p0 - 2 + li;
    xin[ci][li] = (gq >= 0 && gq < 500) ? Y1[((b * 32) + ci) * 500 + gq] : 0.f;
  }
  for (int e = tid; e < 64 * 160; e += 256) {
    int co = e / 160, r = e % 160;
    ws2[co * 161 + r] = Wc2[e];
  }
  __syncthreads();
  int co = tid >> 2, sub = tid & 3;
  int base = sub * 26;
  float acc[26];
  #pragma unroll
  for (int r = 0; r < 26; ++r) acc[r] = 0.f;
  for (int ci = 0; ci < 32; ++ci) {
    float xr[30];
    #pragma unroll
    for (int jj = 0; jj < 30; ++jj) xr[jj] = xin[ci][base + jj];
    #pragma unroll
    for (int k = 0; k < 5; ++k) {
      float wk = ws2[co * 161 + ci * 5 + k];
      #pragma unroll
      for (int r = 0; r < 26; ++r) acc[r] = fmaf(xr[r + k], wk, acc[r]);
    }
  }
  float inv = bn_inv();
  float bc = bc2[co], gc = gc2[co], ec = bec2[co];
  int ps = p0 + sub * 13;
  #pragma unroll
  for (int r = 0; r < 13; ++r) {
    int p = ps + r;
    if (p < 250) {
      float a0 = fmaxf((acc[2 * r] + bc) * inv * gc + ec, 0.f);
      float a1 = fmaxf((acc[2 * r + 1] + bc) * inv * gc + ec, 0.f);
      Y2[((b * 64) + co) * 250 + p] = fmaxf(a0, a1);
    }
  }
}

// ------- conv3 as split-K GEMM: M=64(b) N=128(o) K=16000, partials -------
__global__ __launch_bounds__(256) void k_conv3(
    const float* __restrict__ Y2, const float* __restrict__ Wc3,
    float* __restrict__ C3P, int CP)
{
  int pb = blockIdx.x, tid = threadIdx.x;
  __shared__ float As[64 * 64];        // [b][k]
  __shared__ float Bs[64 * 128];       // [k][o], o-slot XOR-swizzled by k
  int bt = tid >> 5, ot = tid & 31;
  int b0 = bt * 8, o0 = ot * 4;
  float4 acc[8];
  #pragma unroll
  for (int r = 0; r < 8; ++r) acc[r] = make_float4(0.f, 0.f, 0.f, 0.f);

  for (int s = 0; s < CP; ++s) {
    int kbase = (pb * CP + s) * 64;
    __syncthreads();
    for (int e = tid; e < 4096; e += 256) {       // A stage, coalesced, linear
      int bb = e >> 6, kk = e & 63;
      As[e] = Y2[bb * 16000 + kbase + kk];
    }
    for (int e = tid; e < 8192; e += 256) {       // B stage, swizzled dest
      int o = e >> 6, kk = e & 63;
      float v = Wc3[o * 16000 + kbase + kk];
      Bs[kk * 128 + ((((o >> 2) ^ (kk & 31)) << 2) | (o & 3))] = v;
    }
    __syncthreads();
    for (int ks = 0; ks < 64; ks += 4) {
      float4 av[8];
      #pragma unroll
      for (int r = 0; r < 8; ++r)
        av[r] = *(const float4*)&As[(b0 + r) * 64 + ks];
      float4 bv[4];
      #pragma unroll
      for (int q = 0; q < 4; ++q) {
        int kk = ks + q;
        bv[q] = *(const float4*)&Bs[kk * 128 + ((ot ^ (kk & 31)) << 2)];
      }
      #pragma unroll
      for (int q = 0; q < 4; ++q) {
        #pragma unroll
        for (int r = 0; r < 8; ++r) {
          float a = (q == 0) ? av[r].x : (q == 1) ? av[r].y
                  : (q == 2) ? av[r].z : av[r].w;
          acc[r].x = fmaf(a, bv[q].x, acc[r].x);
          acc[r].y = fmaf(a, bv[q].y, acc[r].y);
          acc[r].z = fmaf(a, bv[q].z, acc[r].z);
          acc[r].w = fmaf(a, bv[q].w, acc[r].w);
        }
      }
    }
  }
  #pragma unroll
  for (int r = 0; r < 8; ++r)
    *(float4*)&C3P[(size_t)pb * 8192 + (b0 + r) * 128 + o0] = acc[r];
}

// ------- parallel split-K reduce + bc3, fc1+BN+ReLU, fc2, log_softmax -------
// 256 threads: 8 c-groups x 32 o-quads, float4 loads, LDS tree combine.
__global__ __launch_bounds__(256) void k_fc(
    const float* __restrict__ C3P, const float* __restrict__ bc3,
    const float* __restrict__ Wf, const float* __restrict__ bf,
    const float* __restrict__ gf, const float* __restrict__ bef,
    const float* __restrict__ Wo, const float* __restrict__ bo,
    float* __restrict__ out, int NB)
{
  int b = blockIdx.x, t = threadIdx.x;
  __shared__ float zp[8][128];
  __shared__ float z[128];
  __shared__ float fp[4][64];
  __shared__ float f[64];

  int g = t >> 5;            // c-group 0..7
  int o4 = (t & 31) * 4;     // o-quad
  float4 a = make_float4(0.f, 0.f, 0.f, 0.f);
  for (int c = g; c < NB; c += 8) {
    float4 v = *(const float4*)&C3P[(size_t)c * 8192 + b * 128 + o4];
    a.x += v.x; a.y += v.y; a.z += v.z; a.w += v.w;
  }
  *(float4*)&zp[g][o4] = a;
  __syncthreads();
  if (t < 128) {
    float s = bc3[t];
    #pragma unroll
    for (int gg = 0; gg < 8; ++gg) s += zp[gg][t];
    z[t] = s;
  }
  __syncthreads();

  // fc1: 64 outputs x 4 k-quarters
  {
    int oo = t & 63, q = t >> 6;
    float acc = 0.f;
    #pragma unroll
    for (int k = 0; k < 32; ++k) {
      int kk = q * 32 + k;
      acc = fmaf(z[kk], Wf[kk * 64 + oo], acc);
    }
    fp[q][oo] = acc;
  }
  __syncthreads();
  if (t < 64) {
    float v = fp[0][t] + fp[1][t] + fp[2][t] + fp[3][t] + bf[t];
    v = v * bn_inv() * gf[t] + bef[t];
    f[t] = fmaxf(v, 0.f);
  }
  __syncthreads();

  if (t < 64) {              // wave 0 only: fc2 + log_softmax across 64 lanes
    float logit = 0.f;
    if (t < 12) {
      float acc = 0.f;
      #pragma unroll 8
      for (int k = 0; k < 64; ++k) acc = fmaf(f[k], Wo[k * 12 + t], acc);
      logit = acc + bo[t];
    }
    float m = (t < 12) ? logit : -3.4e38f;
    for (int off = 32; off > 0; off >>= 1) m = fmaxf(m, __shfl_xor(m, off));
    float e = (t < 12) ? expf(logit - m) : 0.f;
    float ssum = e;
    for (int off = 32; off > 0; off >>= 1) ssum += __shfl_xor(ssum, off);
    if (t < 12) out[b * 12 + t] = logit - m - logf(ssum);
  }
}

extern "C" void kernel_launch(void* const* d_in, const int* in_sizes, int n_in,
                              void* d_out, int out_size, void* d_ws, size_t ws_size,
                              hipStream_t stream)
{
  const float* xs   = (const float*)d_in[0];
  const float* xg   = (const float*)d_in[1];
  const float* W1   = (const float*)d_in[2];
  const float* b1   = (const float*)d_in[3];
  const float* gl   = (const float*)d_in[4];
  const float* bl   = (const float*)d_in[5];
  const float* Wg   = (const float*)d_in[6];
  const float* bg   = (const float*)d_in[7];
  const float* g1   = (const float*)d_in[8];
  const float* be1  = (const float*)d_in[9];
  const float* Wc1  = (const float*)d_in[10];
  const float* bc1  = (const float*)d_in[11];
  const float* gc1  = (const float*)d_in[12];
  const float* bec1 = (const float*)d_in[13];
  const float* Wc2  = (const float*)d_in[14];
  const float* bc2  = (const float*)d_in[15];
  const float* gc2  = (const float*)d_in[16];
  const float* bec2 = (const float*)d_in[17];
  const float* Wc3  = (const float*)d_in[18];
  const float* bc3  = (const float*)d_in[19];
  const float* Wf   = (const float*)d_in[20];
  const float* bfp  = (const float*)d_in[21];
  const float* gf   = (const float*)d_in[22];
  const float* bef  = (const float*)d_in[23];
  const float* Wo   = (const float*)d_in[24];
  const float* bo   = (const float*)d_in[25];
  float* out = (float*)d_out;

  float* W   = (float*)d_ws;
  float* X0  = W;                 // 64000 floats
  float* Y1  = W + 64000;         // 1,024,000
  float* Y2  = W + 1088000;       // 1,024,000
  float* C3P = W + 2112000;       // NB*8192

  long availl = (long)(ws_size / 4) - 2112000L;
  const int cand[8] = {250, 125, 50, 25, 10, 5, 2, 1};
  int NB = 1;
  for (int i = 0; i < 8; ++i)
    if ((long)cand[i] * 8192L <= availl) { NB = cand[i]; break; }
  int CP = 250 / NB;

  k_lin1 <<<64, 256, 0, stream>>>(xs, W1, b1, gl, bl, X0);
  k_graph<<<64, 256, 0, stream>>>(xg, Wg, bg, g1, be1, X0);
  k_conv1<<<dim3(64, 4), 256, 0, stream>>>(X0, Wc1, bc1, gc1, bec1, Y1);
  k_conv2<<<dim3(64, 5), 256, 0, stream>>>(Y1, Wc2, bc2, gc2, bec2, Y2);
  k_conv3<<<NB, 256, 0, stream>>>(Y2, Wc3, C3P, CP);
  k_fc   <<<64, 256, 0, stream>>>(C3P, bc3, Wf, bfp, gf, bef, Wo, bo, out, NB);
}

// Round 3
// 200.432 us; speedup vs baseline: 1.6415x; 1.1103x over previous
//
#include <hip/hip_runtime.h>
#include <math.h>

#define NN 750

__device__ __forceinline__ float bn_inv() { return 1.0f / sqrtf(1.0f + 1e-5f); }

// monotone bijection float <-> uint32 (order-preserving)
__device__ __forceinline__ unsigned encf(float f) {
  unsigned b = __float_as_uint(f);
  return (b & 0x80000000u) ? ~b : (b | 0x80000000u);
}
__device__ __forceinline__ float decf(unsigned u) {
  return __uint_as_float((u & 0x80000000u) ? (u & 0x7fffffffu) : ~u);
}

// ---------------- linear1 + BN + ReLU -> X0[b][0..250) ----------------
__global__ __launch_bounds__(256) void k_lin1(
    const float* __restrict__ xs, const float* __restrict__ W1,
    const float* __restrict__ b1, const float* __restrict__ gl,
    const float* __restrict__ bl, float* __restrict__ X0)
{
  int b = blockIdx.x, t = threadIdx.x;
  __shared__ float xsh[250];
  for (int k = t; k < 250; k += 256) xsh[k] = xs[b * 250 + k];
  __syncthreads();
  if (t < 250) {
    float acc = 0.f;
    #pragma unroll 10
    for (int k = 0; k < 250; ++k) acc = fmaf(xsh[k], W1[k * 250 + t], acc);
    float v = (acc + b1[t]) * bn_inv() * gl[t] + bl[t];
    X0[b * 1000 + t] = fmaxf(v, 0.f);
  }
}

// ---- GCN pass 1: per-node rank/lo/hi via threshold counting (no sort) ----
// pred(i,j) = ((d_i-d_j)^2 < 0.01f)  <=>  |fl(d_i-d_j)| < 0.1f (exact, see notes)
// keys k = (encf(d)<<10)|idx form a strict total order; lo/hi are counts below
// the exact float boundaries found by bisection in encoded space.
__global__ __launch_bounds__(256) void k_gcn_count(
    const float* __restrict__ xg, const float* __restrict__ Wg,
    float* __restrict__ szdn, int* __restrict__ loA, int* __restrict__ hiA,
    float* __restrict__ dnA)
{
  int b = blockIdx.x, c = blockIdx.y, t = threadIdx.x;
  __shared__ unsigned long long kL[NN];
  __shared__ float wgs[64];
  for (int j = t; j < NN; j += 256) {
    float dj = xg[(size_t)(b * NN + j) * 8];
    kL[j] = ((unsigned long long)encf(dj) << 10) | (unsigned)j;
  }
  if (t < 64) wgs[t] = Wg[t];
  __syncthreads();
  if (t >= 250) return;
  int i = c * 250 + t;
  float d = xg[(size_t)(b * NN + i) * 8];
  unsigned long long ki = ((unsigned long long)encf(d) << 10) | (unsigned)i;

  // A1 = first u with fl(d - dec(u)) < 0.1f   (f(u) monotone non-increasing)
  unsigned uf = encf(d - 0.15f);   // pred-false side (diff ~0.15 >= 0.1)
  unsigned ut = encf(d);           // pred-true side (diff 0)
  #pragma unroll 1
  for (int it = 0; it < 33 && (ut - uf) > 1u; ++it) {
    unsigned um = uf + ((ut - uf) >> 1);
    if (d - decf(um) >= 0.1f) uf = um; else ut = um;
  }
  unsigned A1 = ut;
  // B = first u with fl(d - dec(u)) <= -0.1f  (g(u) monotone non-decreasing)
  unsigned vf = encf(d);           // g false
  unsigned vt = encf(d + 0.15f);   // g true
  #pragma unroll 1
  for (int it = 0; it < 33 && (vt - vf) > 1u; ++it) {
    unsigned um = vf + ((vt - vf) >> 1);
    if (d - decf(um) <= -0.1f) vt = um; else vf = um;
  }
  unsigned B = vt;

  unsigned long long KA = (unsigned long long)A1 << 10;
  unsigned long long KB = (unsigned long long)B << 10;
  int rank = 0, lov = 0, hiv = 0;
  #pragma unroll 6
  for (int j = 0; j < NN; ++j) {
    unsigned long long kj = kL[j];
    rank += (kj < ki);
    lov  += (kj < KA);
    hiv  += (kj < KB);
  }
  int cnt = hiv - lov;
  float dn = 1.0f / sqrtf((float)cnt);

  const float4* xp = (const float4*)(xg + (size_t)(b * NN + i) * 8);
  float4 x0 = xp[0], x1 = xp[1];
  float xv[8] = {x0.x, x0.y, x0.z, x0.w, x1.x, x1.y, x1.z, x1.w};
  float zf[8];
  #pragma unroll
  for (int f = 0; f < 8; ++f) {
    float a = 0.f;
    #pragma unroll
    for (int k = 0; k < 8; ++k) a = fmaf(xv[k], wgs[k * 8 + f], a);
    zf[f] = dn * a;
  }
  float* dst = szdn + ((size_t)b * NN + rank) * 8;
  *(float4*)dst       = make_float4(zf[0], zf[1], zf[2], zf[3]);
  *(float4*)(dst + 4) = make_float4(zf[4], zf[5], zf[6], zf[7]);
  loA[b * NN + i] = lov; hiA[b * NN + i] = hiv; dnA[b * NN + i] = dn;
}

// ---- GCN pass 2: prefix-sum sorted zdn, range-diff gather, BN+ReLU+mean ----
__global__ __launch_bounds__(512) void k_gcn_apply(
    const float* __restrict__ szdn, const int* __restrict__ loA,
    const int* __restrict__ hiA, const float* __restrict__ dnA,
    const float* __restrict__ bgp, const float* __restrict__ g1p,
    const float* __restrict__ be1p, float* __restrict__ X0)
{
  int b = blockIdx.x, t = threadIdx.x;
  __shared__ float P[NN * 8];      // 24000 B, becomes inclusive prefix
  __shared__ float wsum[4 * 8];
  __shared__ float bgs[8];
  if (t < 8) bgs[t] = bgp[t];
  for (int e = t; e < NN * 2; e += 512)
    ((float4*)P)[e] = ((const float4*)(szdn + (size_t)b * NN * 8))[e];
  __syncthreads();                               // B1

  int lane = t & 63, w = t >> 6;
  bool scanner = (t < 256);
  float e0[8], e01[8], s[8], sc[8];
  if (scanner) {
    int u = t;
    if (u < 250) {
      #pragma unroll
      for (int f = 0; f < 8; ++f) e0[f] = P[(3 * u) * 8 + f];
      #pragma unroll
      for (int f = 0; f < 8; ++f) e01[f] = e0[f] + P[(3 * u + 1) * 8 + f];
      #pragma unroll
      for (int f = 0; f < 8; ++f) s[f] = e01[f] + P[(3 * u + 2) * 8 + f];
    } else {
      #pragma unroll
      for (int f = 0; f < 8; ++f) { e0[f] = 0.f; e01[f] = 0.f; s[f] = 0.f; }
    }
    #pragma unroll
    for (int f = 0; f < 8; ++f) sc[f] = s[f];
    for (int dlt = 1; dlt < 64; dlt <<= 1) {
      float o[8];
      #pragma unroll
      for (int f = 0; f < 8; ++f) o[f] = __shfl_up(sc[f], (unsigned)dlt, 64);
      if (lane >= dlt) {
        #pragma unroll
        for (int f = 0; f < 8; ++f) sc[f] += o[f];
      }
    }
    if (lane == 63) {
      #pragma unroll
      for (int f = 0; f < 8; ++f) wsum[w * 8 + f] = sc[f];
    }
  }
  __syncthreads();                               // B2 (P reads done; wsum ready)
  if (scanner && t < 250) {
    float off[8];
    #pragma unroll
    for (int f = 0; f < 8; ++f) off[f] = 0.f;
    for (int ww = 0; ww < w; ++ww) {
      #pragma unroll
      for (int f = 0; f < 8; ++f) off[f] += wsum[ww * 8 + f];
    }
    int u = t;
    #pragma unroll
    for (int f = 0; f < 8; ++f) {
      float excl = sc[f] - s[f] + off[f];
      P[(3 * u) * 8 + f]     = excl + e0[f];
      P[(3 * u + 1) * 8 + f] = excl + e01[f];
      P[(3 * u + 2) * 8 + f] = excl + s[f];
    }
  }
  __syncthreads();                               // B3

  float inv = bn_inv(), g1v = g1p[0], be1v = be1p[0];
  for (int nn = t; nn < NN; nn += 512) {
    int lo = loA[b * NN + nn], hi = hiA[b * NN + nn];
    float dn = dnA[b * NN + nn];
    float gsum = 0.f;
    #pragma unroll
    for (int f = 0; f < 8; ++f) {
      float a  = P[(hi - 1) * 8 + f];
      float bb = (lo > 0) ? P[(lo - 1) * 8 + f] : 0.f;
      float h  = dn * (a - bb) + bgs[f];
      float v  = h * inv * g1v + be1v;
      gsum += fmaxf(v, 0.f);
    }
    X0[b * 1000 + 250 + nn] = gsum * 0.125f;
  }
}

// ---------------- conv1 (1->32,k5,pad2) + BN + ReLU + pool2 ----------------
__global__ __launch_bounds__(256) void k_conv1(
    const float* __restrict__ X0, const float* __restrict__ Wc1,
    const float* __restrict__ bc1, const float* __restrict__ gc1,
    const float* __restrict__ bec1, float* __restrict__ Y1)
{
  int b = blockIdx.x, p0 = blockIdx.y * 125, tid = threadIdx.x;
  __shared__ float xsh[254];
  __shared__ float w[160], bb[32], gg[32], ee[32];
  for (int i = tid; i < 254; i += 256) {
    int gq = 2 * p0 - 2 + i;
    xsh[i] = (gq >= 0 && gq < 1000) ? X0[b * 1000 + gq] : 0.f;
  }
  for (int i = tid; i < 160; i += 256) w[i] = Wc1[i];
  if (tid < 32) { bb[tid] = bc1[tid]; gg[tid] = gc1[tid]; ee[tid] = bec1[tid]; }
  __syncthreads();
  float inv = bn_inv();
  for (int o = tid; o < 32 * 125; o += 256) {
    int c = o / 125, pl = o % 125;
    int base = 2 * pl;
    float v0 = 0.f, v1 = 0.f;
    #pragma unroll
    for (int k = 0; k < 5; ++k) {
      float wk = w[c * 5 + k];
      v0 = fmaf(xsh[base + k], wk, v0);
      v1 = fmaf(xsh[base + 1 + k], wk, v1);
    }
    float s0 = fmaxf((v0 + bb[c]) * inv * gg[c] + ee[c], 0.f);
    float s1 = fmaxf((v1 + bb[c]) * inv * gg[c] + ee[c], 0.f);
    Y1[((b * 32) + c) * 500 + p0 + pl] = fmaxf(s0, s1);
  }
}

// ---------------- conv2 (32->64,k5,pad2) + BN + ReLU + pool2 ----------------
__global__ __launch_bounds__(256) void k_conv2(
    const float* __restrict__ Y1, const float* __restrict__ Wc2,
    const float* __restrict__ bc2, const float* __restrict__ gc2,
    const float* __restrict__ bec2, float* __restrict__ Y2)
{
  int b = blockIdx.x, p0 = blockIdx.y * 52, tid = threadIdx.x;
  __shared__ float xin[32][108];
  __shared__ float ws2[64 * 161];
  for (int e = tid; e < 32 * 108; e += 256) {
    int ci = e / 108, li = e % 108;
    int gq = 2 * p0 - 2 + li;
    xin[ci][li] = (gq >= 0 && gq < 500) ? Y1[((b * 32) + ci) * 500 + gq] : 0.f;
  }
  for (int e = tid; e < 64 * 160; e += 256) {
    int co = e / 160, r = e % 160;
    ws2[co * 161 + r] = Wc2[e];
  }
  __syncthreads();
  int co = tid >> 2, sub = tid & 3;
  int base = sub * 26;
  float acc[26];
  #pragma unroll
  for (int r = 0; r < 26; ++r) acc[r] = 0.f;
  for (int ci = 0; ci < 32; ++ci) {
    float xr[30];
    #pragma unroll
    for (int jj = 0; jj < 30; ++jj) xr[jj] = xin[ci][base + jj];
    #pragma unroll
    for (int k = 0; k < 5; ++k) {
      float wk = ws2[co * 161 + ci * 5 + k];
      #pragma unroll
      for (int r = 0; r < 26; ++r) acc[r] = fmaf(xr[r + k], wk, acc[r]);
    }
  }
  float inv = bn_inv();
  float bc = bc2[co], gc = gc2[co], ec = bec2[co];
  int ps = p0 + sub * 13;
  #pragma unroll
  for (int r = 0; r < 13; ++r) {
    int p = ps + r;
    if (p < 250) {
      float a0 = fmaxf((acc[2 * r] + bc) * inv * gc + ec, 0.f);
      float a1 = fmaxf((acc[2 * r + 1] + bc) * inv * gc + ec, 0.f);
      Y2[((b * 64) + co) * 250 + p] = fmaxf(a0, a1);
    }
  }
}

// ------- conv3 as split-K GEMM: M=64(b) N=128(o) K=16000, partials -------
__global__ __launch_bounds__(256) void k_conv3(
    const float* __restrict__ Y2, const float* __restrict__ Wc3,
    float* __restrict__ C3P, int CP)
{
  int pb = blockIdx.x, tid = threadIdx.x;
  __shared__ float As[64 * 64];
  __shared__ float Bs[64 * 128];
  int bt = tid >> 5, ot = tid & 31;
  int b0 = bt * 8, o0 = ot * 4;
  float4 acc[8];
  #pragma unroll
  for (int r = 0; r < 8; ++r) acc[r] = make_float4(0.f, 0.f, 0.f, 0.f);

  for (int s = 0; s < CP; ++s) {
    int kbase = (pb * CP + s) * 64;
    __syncthreads();
    for (int e = tid; e < 4096; e += 256) {
      int bb = e >> 6, kk = e & 63;
      As[e] = Y2[bb * 16000 + kbase + kk];
    }
    for (int e = tid; e < 8192; e += 256) {
      int o = e >> 6, kk = e & 63;
      float v = Wc3[o * 16000 + kbase + kk];
      Bs[kk * 128 + ((((o >> 2) ^ (kk & 31)) << 2) | (o & 3))] = v;
    }
    __syncthreads();
    for (int ks = 0; ks < 64; ks += 4) {
      float4 av[8];
      #pragma unroll
      for (int r = 0; r < 8; ++r)
        av[r] = *(const float4*)&As[(b0 + r) * 64 + ks];
      float4 bv[4];
      #pragma unroll
      for (int q = 0; q < 4; ++q) {
        int kk = ks + q;
        bv[q] = *(const float4*)&Bs[kk * 128 + ((ot ^ (kk & 31)) << 2)];
      }
      #pragma unroll
      for (int q = 0; q < 4; ++q) {
        #pragma unroll
        for (int r = 0; r < 8; ++r) {
          float a = (q == 0) ? av[r].x : (q == 1) ? av[r].y
                  : (q == 2) ? av[r].z : av[r].w;
          acc[r].x = fmaf(a, bv[q].x, acc[r].x);
          acc[r].y = fmaf(a, bv[q].y, acc[r].y);
          acc[r].z = fmaf(a, bv[q].z, acc[r].z);
          acc[r].w = fmaf(a, bv[q].w, acc[r].w);
        }
      }
    }
  }
  #pragma unroll
  for (int r = 0; r < 8; ++r)
    *(float4*)&C3P[(size_t)pb * 8192 + (b0 + r) * 128 + o0] = acc[r];
}

// ------- parallel split-K reduce + bc3, fc1+BN+ReLU, fc2, log_softmax -------
__global__ __launch_bounds__(256) void k_fc(
    const float* __restrict__ C3P, const float* __restrict__ bc3,
    const float* __restrict__ Wf, const float* __restrict__ bf,
    const float* __restrict__ gf, const float* __restrict__ bef,
    const float* __restrict__ Wo, const float* __restrict__ bo,
    float* __restrict__ out, int NB)
{
  int b = blockIdx.x, t = threadIdx.x;
  __shared__ float zp[8][128];
  __shared__ float z[128];
  __shared__ float fp[4][64];
  __shared__ float f[64];

  int g = t >> 5;
  int o4 = (t & 31) * 4;
  float4 a = make_float4(0.f, 0.f, 0.f, 0.f);
  for (int c = g; c < NB; c += 8) {
    float4 v = *(const float4*)&C3P[(size_t)c * 8192 + b * 128 + o4];
    a.x += v.x; a.y += v.y; a.z += v.z; a.w += v.w;
  }
  *(float4*)&zp[g][o4] = a;
  __syncthreads();
  if (t < 128) {
    float s = bc3[t];
    #pragma unroll
    for (int gg = 0; gg < 8; ++gg) s += zp[gg][t];
    z[t] = s;
  }
  __syncthreads();
  {
    int oo = t & 63, q = t >> 6;
    float acc = 0.f;
    #pragma unroll
    for (int k = 0; k < 32; ++k) {
      int kk = q * 32 + k;
      acc = fmaf(z[kk], Wf[kk * 64 + oo], acc);
    }
    fp[q][oo] = acc;
  }
  __syncthreads();
  if (t < 64) {
    float v = fp[0][t] + fp[1][t] + fp[2][t] + fp[3][t] + bf[t];
    v = v * bn_inv() * gf[t] + bef[t];
    f[t] = fmaxf(v, 0.f);
  }
  __syncthreads();

  if (t < 64) {
    float logit = 0.f;
    if (t < 12) {
      float acc = 0.f;
      #pragma unroll 8
      for (int k = 0; k < 64; ++k) acc = fmaf(f[k], Wo[k * 12 + t], acc);
      logit = acc + bo[t];
    }
    float m = (t < 12) ? logit : -3.4e38f;
    for (int off = 32; off > 0; off >>= 1) m = fmaxf(m, __shfl_xor(m, off));
    float e = (t < 12) ? expf(logit - m) : 0.f;
    float ssum = e;
    for (int off = 32; off > 0; off >>= 1) ssum += __shfl_xor(ssum, off);
    if (t < 12) out[b * 12 + t] = logit - m - logf(ssum);
  }
}

extern "C" void kernel_launch(void* const* d_in, const int* in_sizes, int n_in,
                              void* d_out, int out_size, void* d_ws, size_t ws_size,
                              hipStream_t stream)
{
  const float* xs   = (const float*)d_in[0];
  const float* xg   = (const float*)d_in[1];
  const float* W1   = (const float*)d_in[2];
  const float* b1   = (const float*)d_in[3];
  const float* gl   = (const float*)d_in[4];
  const float* bl   = (const float*)d_in[5];
  const float* Wg   = (const float*)d_in[6];
  const float* bg   = (const float*)d_in[7];
  const float* g1   = (const float*)d_in[8];
  const float* be1  = (const float*)d_in[9];
  const float* Wc1  = (const float*)d_in[10];
  const float* bc1  = (const float*)d_in[11];
  const float* gc1  = (const float*)d_in[12];
  const float* bec1 = (const float*)d_in[13];
  const float* Wc2  = (const float*)d_in[14];
  const float* bc2  = (const float*)d_in[15];
  const float* gc2  = (const float*)d_in[16];
  const float* bec2 = (const float*)d_in[17];
  const float* Wc3  = (const float*)d_in[18];
  const float* bc3  = (const float*)d_in[19];
  const float* Wf   = (const float*)d_in[20];
  const float* bfp  = (const float*)d_in[21];
  const float* gf   = (const float*)d_in[22];
  const float* bef  = (const float*)d_in[23];
  const float* Wo   = (const float*)d_in[24];
  const float* bo   = (const float*)d_in[25];
  float* out = (float*)d_out;

  float* W    = (float*)d_ws;
  float* X0   = W;                      // 64000
  float* Y1   = W + 64000;              // 1,024,000
  float* Y2   = W + 1088000;            // 1,024,000
  float* szdn = W + 2112000;            // 384,000
  int*   loA  = (int*)(W + 2496000);    // 48,000
  int*   hiA  = (int*)(W + 2544000);    // 48,000
  float* dnA  = W + 2592000;            // 48,000
  float* C3P  = W + 2640000;            // NB*8192

  long availl = (long)(ws_size / 4) - 2640000L;
  const int cand[8] = {250, 125, 50, 25, 10, 5, 2, 1};
  int NB = 1;
  for (int i = 0; i < 8; ++i)
    if ((long)cand[i] * 8192L <= availl) { NB = cand[i]; break; }
  int CP = 250 / NB;

  k_lin1     <<<64, 256, 0, stream>>>(xs, W1, b1, gl, bl, X0);
  k_gcn_count<<<dim3(64, 3), 256, 0, stream>>>(xg, Wg, szdn, loA, hiA, dnA);
  k_gcn_apply<<<64, 512, 0, stream>>>(szdn, loA, hiA, dnA, bg, g1, be1, X0);
  k_conv1    <<<dim3(64, 4), 256, 0, stream>>>(X0, Wc1, bc1, gc1, bec1, Y1);
  k_conv2    <<<dim3(64, 5), 256, 0, stream>>>(Y1, Wc2, bc2, gc2, bec2, Y2);
  k_conv3    <<<NB, 256, 0, stream>>>(Y2, Wc3, C3P, CP);
  k_fc       <<<64, 256, 0, stream>>>(C3P, bc3, Wf, bfp, gf, bef, Wo, bo, out, NB);
}

// Round 4
// 194.339 us; speedup vs baseline: 1.6929x; 1.0313x over previous
//
#include <hip/hip_runtime.h>
#include <math.h>

#define NN 750

__device__ __forceinline__ float bn_inv() { return 1.0f / sqrtf(1.0f + 1e-5f); }

// monotone bijection float <-> uint32 (order-preserving)
__device__ __forceinline__ unsigned encf(float f) {
  unsigned b = __float_as_uint(f);
  return (b & 0x80000000u) ? ~b : (b | 0x80000000u);
}
__device__ __forceinline__ float decf(unsigned u) {
  return __uint_as_float((u & 0x80000000u) ? (u & 0x7fffffffu) : ~u);
}

// ---- front: blockIdx.y==3 -> linear1+BN+ReLU (X0s[b][250])
//      blockIdx.y<3  -> GCN pass 1 (rank/lo/hi counting, no sort) ----
__global__ __launch_bounds__(256) void k_front(
    const float* __restrict__ xs, const float* __restrict__ W1,
    const float* __restrict__ b1, const float* __restrict__ gl,
    const float* __restrict__ bl, const float* __restrict__ xg,
    const float* __restrict__ Wg, float* __restrict__ X0s,
    float* __restrict__ szdn, int* __restrict__ loA, int* __restrict__ hiA,
    float* __restrict__ dnA)
{
  int b = blockIdx.x, t = threadIdx.x;
  __shared__ unsigned long long kL[NN];
  __shared__ float wgs[64];
  __shared__ float xsh[250];

  if (blockIdx.y == 3) {            // ---- linear1 ----
    for (int k = t; k < 250; k += 256) xsh[k] = xs[b * 250 + k];
    __syncthreads();
    if (t < 250) {
      float acc = 0.f;
      #pragma unroll 10
      for (int k = 0; k < 250; ++k) acc = fmaf(xsh[k], W1[k * 250 + t], acc);
      float v = (acc + b1[t]) * bn_inv() * gl[t] + bl[t];
      X0s[b * 250 + t] = fmaxf(v, 0.f);
    }
    return;
  }
  // ---- GCN count ----
  int c = blockIdx.y;
  for (int j = t; j < NN; j += 256) {
    float dj = xg[(size_t)(b * NN + j) * 8];
    kL[j] = ((unsigned long long)encf(dj) << 10) | (unsigned)j;
  }
  if (t < 64) wgs[t] = Wg[t];
  __syncthreads();
  if (t >= 250) return;
  int i = c * 250 + t;
  float d = xg[(size_t)(b * NN + i) * 8];
  unsigned long long ki = ((unsigned long long)encf(d) << 10) | (unsigned)i;

  // A1 = first u with fl(d - dec(u)) < 0.1f
  unsigned uf = encf(d - 0.15f), ut = encf(d);
  #pragma unroll 1
  for (int it = 0; it < 33 && (ut - uf) > 1u; ++it) {
    unsigned um = uf + ((ut - uf) >> 1);
    if (d - decf(um) >= 0.1f) uf = um; else ut = um;
  }
  unsigned A1 = ut;
  // B = first u with fl(d - dec(u)) <= -0.1f
  unsigned vf = encf(d), vt = encf(d + 0.15f);
  #pragma unroll 1
  for (int it = 0; it < 33 && (vt - vf) > 1u; ++it) {
    unsigned um = vf + ((vt - vf) >> 1);
    if (d - decf(um) <= -0.1f) vt = um; else vf = um;
  }
  unsigned B = vt;

  unsigned long long KA = (unsigned long long)A1 << 10;
  unsigned long long KB = (unsigned long long)B << 10;
  int rank = 0, lov = 0, hiv = 0;
  #pragma unroll 6
  for (int j = 0; j < NN; ++j) {
    unsigned long long kj = kL[j];
    rank += (kj < ki);
    lov  += (kj < KA);
    hiv  += (kj < KB);
  }
  int cnt = hiv - lov;
  float dn = 1.0f / sqrtf((float)cnt);

  const float4* xp = (const float4*)(xg + (size_t)(b * NN + i) * 8);
  float4 x0 = xp[0], x1 = xp[1];
  float xv[8] = {x0.x, x0.y, x0.z, x0.w, x1.x, x1.y, x1.z, x1.w};
  float zf[8];
  #pragma unroll
  for (int f = 0; f < 8; ++f) {
    float a = 0.f;
    #pragma unroll
    for (int k = 0; k < 8; ++k) a = fmaf(xv[k], wgs[k * 8 + f], a);
    zf[f] = dn * a;
  }
  float* dst = szdn + ((size_t)b * NN + rank) * 8;
  *(float4*)dst       = make_float4(zf[0], zf[1], zf[2], zf[3]);
  *(float4*)(dst + 4) = make_float4(zf[4], zf[5], zf[6], zf[7]);
  loA[b * NN + i] = lov; hiA[b * NN + i] = hiv; dnA[b * NN + i] = dn;
}

// ---- GCN pass 2 (scan + range-diff + BN/ReLU/mean) fused with conv1 ----
__global__ __launch_bounds__(512) void k_apply1(
    const float* __restrict__ szdn, const int* __restrict__ loA,
    const int* __restrict__ hiA, const float* __restrict__ dnA,
    const float* __restrict__ bgp, const float* __restrict__ g1p,
    const float* __restrict__ be1p, const float* __restrict__ X0s,
    const float* __restrict__ Wc1, const float* __restrict__ bc1,
    const float* __restrict__ gc1, const float* __restrict__ bec1,
    float* __restrict__ Y1)
{
  int b = blockIdx.x, t = threadIdx.x;
  __shared__ float P[NN * 8];      // inclusive prefix (24 KB)
  __shared__ float wsum[4 * 8];
  __shared__ float bgs[8];
  __shared__ float xpad[1004];     // padded concat vector
  __shared__ float w1s[160], bb1[32], gg1[32], ee1[32];

  if (t < 8) bgs[t] = bgp[t];
  for (int i = t; i < 160; i += 512) w1s[i] = Wc1[i];
  if (t >= 256 && t < 288) {
    int q = t - 256; bb1[q] = bc1[q]; gg1[q] = gc1[q]; ee1[q] = bec1[q];
  }
  if (t >= 288 && t < 292) xpad[(t - 288) < 2 ? (t - 288) : (1000 + t - 288)] = 0.f;
  if (t < 250) xpad[2 + t] = X0s[b * 250 + t];
  for (int e = t; e < NN * 2; e += 512)
    ((float4*)P)[e] = ((const float4*)(szdn + (size_t)b * NN * 8))[e];
  __syncthreads();                               // B1

  int lane = t & 63, w = t >> 6;
  bool scanner = (t < 256);
  float e0[8], e01[8], s[8], sc[8];
  if (scanner) {
    int u = t;
    if (u < 250) {
      #pragma unroll
      for (int f = 0; f < 8; ++f) e0[f] = P[(3 * u) * 8 + f];
      #pragma unroll
      for (int f = 0; f < 8; ++f) e01[f] = e0[f] + P[(3 * u + 1) * 8 + f];
      #pragma unroll
      for (int f = 0; f < 8; ++f) s[f] = e01[f] + P[(3 * u + 2) * 8 + f];
    } else {
      #pragma unroll
      for (int f = 0; f < 8; ++f) { e0[f] = 0.f; e01[f] = 0.f; s[f] = 0.f; }
    }
    #pragma unroll
    for (int f = 0; f < 8; ++f) sc[f] = s[f];
    for (int dlt = 1; dlt < 64; dlt <<= 1) {
      float o[8];
      #pragma unroll
      for (int f = 0; f < 8; ++f) o[f] = __shfl_up(sc[f], (unsigned)dlt, 64);
      if (lane >= dlt) {
        #pragma unroll
        for (int f = 0; f < 8; ++f) sc[f] += o[f];
      }
    }
    if (lane == 63) {
      #pragma unroll
      for (int f = 0; f < 8; ++f) wsum[w * 8 + f] = sc[f];
    }
  }
  __syncthreads();                               // B2
  if (scanner && t < 250) {
    float off[8];
    #pragma unroll
    for (int f = 0; f < 8; ++f) off[f] = 0.f;
    for (int ww = 0; ww < w; ++ww) {
      #pragma unroll
      for (int f = 0; f < 8; ++f) off[f] += wsum[ww * 8 + f];
    }
    int u = t;
    #pragma unroll
    for (int f = 0; f < 8; ++f) {
      float excl = sc[f] - s[f] + off[f];
      P[(3 * u) * 8 + f]     = excl + e0[f];
      P[(3 * u + 1) * 8 + f] = excl + e01[f];
      P[(3 * u + 2) * 8 + f] = excl + s[f];
    }
  }
  __syncthreads();                               // B3

  float inv = bn_inv(), g1v = g1p[0], be1v = be1p[0];
  for (int nn = t; nn < NN; nn += 512) {
    int lo = loA[b * NN + nn], hi = hiA[b * NN + nn];
    float dn = dnA[b * NN + nn];
    float gsum = 0.f;
    #pragma unroll
    for (int f = 0; f < 8; ++f) {
      float a  = P[(hi - 1) * 8 + f];
      float bb = (lo > 0) ? P[(lo - 1) * 8 + f] : 0.f;
      float h  = dn * (a - bb) + bgs[f];
      float v  = h * inv * g1v + be1v;
      gsum += fmaxf(v, 0.f);
    }
    xpad[2 + 250 + nn] = gsum * 0.125f;
  }
  __syncthreads();                               // B4

  // conv1 (1->32,k5,pad2)+BN+ReLU+pool2 from xpad -> Y1[b][32][500]
  for (int o = t; o < 32 * 500; o += 512) {
    int c = o / 500, pl = o % 500;
    int q = 2 * pl;
    float v0 = 0.f, v1 = 0.f;
    #pragma unroll
    for (int k = 0; k < 5; ++k) {
      float wk = w1s[c * 5 + k];
      v0 = fmaf(xpad[q + k], wk, v0);
      v1 = fmaf(xpad[q + 1 + k], wk, v1);
    }
    float s0 = fmaxf((v0 + bb1[c]) * inv * gg1[c] + ee1[c], 0.f);
    float s1 = fmaxf((v1 + bb1[c]) * inv * gg1[c] + ee1[c], 0.f);
    Y1[((b * 32) + c) * 500 + pl] = fmaxf(s0, s1);
  }
}

// ---------------- conv2 (32->64,k5,pad2) + BN + ReLU + pool2 ----------------
__global__ __launch_bounds__(256) void k_conv2(
    const float* __restrict__ Y1, const float* __restrict__ Wc2,
    const float* __restrict__ bc2, const float* __restrict__ gc2,
    const float* __restrict__ bec2, float* __restrict__ Y2)
{
  int b = blockIdx.x, p0 = blockIdx.y * 52, tid = threadIdx.x;
  __shared__ float xin[32][108];
  __shared__ float ws2[64 * 161];
  for (int e = tid; e < 32 * 108; e += 256) {
    int ci = e / 108, li = e % 108;
    int gq = 2 * p0 - 2 + li;
    xin[ci][li] = (gq >= 0 && gq < 500) ? Y1[((b * 32) + ci) * 500 + gq] : 0.f;
  }
  for (int e = tid; e < 64 * 160; e += 256) {
    int co = e / 160, r = e % 160;
    ws2[co * 161 + r] = Wc2[e];
  }
  __syncthreads();
  int co = tid >> 2, sub = tid & 3;
  int base = sub * 26;
  float acc[26];
  #pragma unroll
  for (int r = 0; r < 26; ++r) acc[r] = 0.f;
  for (int ci = 0; ci < 32; ++ci) {
    float xr[30];
    #pragma unroll
    for (int jj = 0; jj < 30; ++jj) xr[jj] = xin[ci][base + jj];
    #pragma unroll
    for (int k = 0; k < 5; ++k) {
      float wk = ws2[co * 161 + ci * 5 + k];
      #pragma unroll
      for (int r = 0; r < 26; ++r) acc[r] = fmaf(xr[r + k], wk, acc[r]);
    }
  }
  float inv = bn_inv();
  float bc = bc2[co], gc = gc2[co], ec = bec2[co];
  int ps = p0 + sub * 13;
  #pragma unroll
  for (int r = 0; r < 13; ++r) {
    int p = ps + r;
    if (p < 250) {
      float a0 = fmaxf((acc[2 * r] + bc) * inv * gc + ec, 0.f);
      float a1 = fmaxf((acc[2 * r + 1] + bc) * inv * gc + ec, 0.f);
      Y2[((b * 64) + co) * 250 + p] = fmaxf(a0, a1);
    }
  }
}

// ------- conv3 split-K GEMM, partials in [b][pb][o] layout -------
__global__ __launch_bounds__(256) void k_conv3(
    const float* __restrict__ Y2, const float* __restrict__ Wc3,
    float* __restrict__ C3P, int CP, int NB)
{
  int pb = blockIdx.x, tid = threadIdx.x;
  __shared__ float As[64 * 64];
  __shared__ float Bs[64 * 128];
  int bt = tid >> 5, ot = tid & 31;
  int b0 = bt * 8, o0 = ot * 4;
  float4 acc[8];
  #pragma unroll
  for (int r = 0; r < 8; ++r) acc[r] = make_float4(0.f, 0.f, 0.f, 0.f);

  for (int s = 0; s < CP; ++s) {
    int kbase = (pb * CP + s) * 64;
    __syncthreads();
    for (int e = tid; e < 4096; e += 256) {
      int bb = e >> 6, kk = e & 63;
      As[e] = Y2[bb * 16000 + kbase + kk];
    }
    for (int e = tid; e < 8192; e += 256) {
      int o = e >> 6, kk = e & 63;
      float v = Wc3[o * 16000 + kbase + kk];
      Bs[kk * 128 + ((((o >> 2) ^ (kk & 31)) << 2) | (o & 3))] = v;
    }
    __syncthreads();
    for (int ks = 0; ks < 64; ks += 4) {
      float4 av[8];
      #pragma unroll
      for (int r = 0; r < 8; ++r)
        av[r] = *(const float4*)&As[(b0 + r) * 64 + ks];
      float4 bv[4];
      #pragma unroll
      for (int q = 0; q < 4; ++q) {
        int kk = ks + q;
        bv[q] = *(const float4*)&Bs[kk * 128 + ((ot ^ (kk & 31)) << 2)];
      }
      #pragma unroll
      for (int q = 0; q < 4; ++q) {
        #pragma unroll
        for (int r = 0; r < 8; ++r) {
          float a = (q == 0) ? av[r].x : (q == 1) ? av[r].y
                  : (q == 2) ? av[r].z : av[r].w;
          acc[r].x = fmaf(a, bv[q].x, acc[r].x);
          acc[r].y = fmaf(a, bv[q].y, acc[r].y);
          acc[r].z = fmaf(a, bv[q].z, acc[r].z);
          acc[r].w = fmaf(a, bv[q].w, acc[r].w);
        }
      }
    }
  }
  #pragma unroll
  for (int r = 0; r < 8; ++r)
    *(float4*)&C3P[((size_t)(b0 + r) * NB + pb) * 128 + o0] = acc[r];
}

// ------- coalesced split-K reduce + bc3, fc1+BN+ReLU, fc2, log_softmax -------
__global__ __launch_bounds__(256) void k_fc(
    const float* __restrict__ C3P, const float* __restrict__ bc3,
    const float* __restrict__ Wf, const float* __restrict__ bf,
    const float* __restrict__ gf, const float* __restrict__ bef,
    const float* __restrict__ Wo, const float* __restrict__ bo,
    float* __restrict__ out, int NB)
{
  int b = blockIdx.x, t = threadIdx.x;
  __shared__ float zp[8][128];
  __shared__ float z[128];
  __shared__ float fp[4][64];
  __shared__ float f[64];

  int g = t >> 5;
  int o4 = (t & 31) * 4;
  float4 a = make_float4(0.f, 0.f, 0.f, 0.f);
  for (int c = g; c < NB; c += 8) {      // contiguous [b][c][o] stream
    float4 v = *(const float4*)&C3P[((size_t)b * NB + c) * 128 + o4];
    a.x += v.x; a.y += v.y; a.z += v.z; a.w += v.w;
  }
  *(float4*)&zp[g][o4] = a;
  __syncthreads();
  if (t < 128) {
    float s = bc3[t];
    #pragma unroll
    for (int gg = 0; gg < 8; ++gg) s += zp[gg][t];
    z[t] = s;
  }
  __syncthreads();
  {
    int oo = t & 63, q = t >> 6;
    float acc = 0.f;
    #pragma unroll
    for (int k = 0; k < 32; ++k) {
      int kk = q * 32 + k;
      acc = fmaf(z[kk], Wf[kk * 64 + oo], acc);
    }
    fp[q][oo] = acc;
  }
  __syncthreads();
  if (t < 64) {
    float v = fp[0][t] + fp[1][t] + fp[2][t] + fp[3][t] + bf[t];
    v = v * bn_inv() * gf[t] + bef[t];
    f[t] = fmaxf(v, 0.f);
  }
  __syncthreads();

  if (t < 64) {
    float logit = 0.f;
    if (t < 12) {
      float acc = 0.f;
      #pragma unroll 8
      for (int k = 0; k < 64; ++k) acc = fmaf(f[k], Wo[k * 12 + t], acc);
      logit = acc + bo[t];
    }
    float m = (t < 12) ? logit : -3.4e38f;
    for (int off = 32; off > 0; off >>= 1) m = fmaxf(m, __shfl_xor(m, off));
    float e = (t < 12) ? expf(logit - m) : 0.f;
    float ssum = e;
    for (int off = 32; off > 0; off >>= 1) ssum += __shfl_xor(ssum, off);
    if (t < 12) out[b * 12 + t] = logit - m - logf(ssum);
  }
}

extern "C" void kernel_launch(void* const* d_in, const int* in_sizes, int n_in,
                              void* d_out, int out_size, void* d_ws, size_t ws_size,
                              hipStream_t stream)
{
  const float* xs   = (const float*)d_in[0];
  const float* xg   = (const float*)d_in[1];
  const float* W1   = (const float*)d_in[2];
  const float* b1   = (const float*)d_in[3];
  const float* gl   = (const float*)d_in[4];
  const float* bl   = (const float*)d_in[5];
  const float* Wg   = (const float*)d_in[6];
  const float* bg   = (const float*)d_in[7];
  const float* g1   = (const float*)d_in[8];
  const float* be1  = (const float*)d_in[9];
  const float* Wc1  = (const float*)d_in[10];
  const float* bc1  = (const float*)d_in[11];
  const float* gc1  = (const float*)d_in[12];
  const float* bec1 = (const float*)d_in[13];
  const float* Wc2  = (const float*)d_in[14];
  const float* bc2  = (const float*)d_in[15];
  const float* gc2  = (const float*)d_in[16];
  const float* bec2 = (const float*)d_in[17];
  const float* Wc3  = (const float*)d_in[18];
  const float* bc3  = (const float*)d_in[19];
  const float* Wf   = (const float*)d_in[20];
  const float* bfp  = (const float*)d_in[21];
  const float* gf   = (const float*)d_in[22];
  const float* bef  = (const float*)d_in[23];
  const float* Wo   = (const float*)d_in[24];
  const float* bo   = (const float*)d_in[25];
  float* out = (float*)d_out;

  float* W    = (float*)d_ws;
  float* X0s  = W;                      // 16,000
  float* Y1   = W + 16000;              // 1,024,000
  float* Y2   = W + 1040000;            // 1,024,000
  float* szdn = W + 2064000;            // 384,000
  int*   loA  = (int*)(W + 2448000);    // 48,000
  int*   hiA  = (int*)(W + 2496000);    // 48,000
  float* dnA  = W + 2544000;            // 48,000
  float* C3P  = W + 2592000;            // NB*8192

  long availl = (long)(ws_size / 4) - 2592000L;
  const int cand[8] = {250, 125, 50, 25, 10, 5, 2, 1};
  int NB = 1;
  for (int i = 0; i < 8; ++i)
    if ((long)cand[i] * 8192L <= availl) { NB = cand[i]; break; }
  int CP = 250 / NB;

  k_front <<<dim3(64, 4), 256, 0, stream>>>(xs, W1, b1, gl, bl, xg, Wg,
                                            X0s, szdn, loA, hiA, dnA);
  k_apply1<<<64, 512, 0, stream>>>(szdn, loA, hiA, dnA, bg, g1, be1,
                                   X0s, Wc1, bc1, gc1, bec1, Y1);
  k_conv2 <<<dim3(64, 5), 256, 0, stream>>>(Y1, Wc2, bc2, gc2, bec2, Y2);
  k_conv3 <<<NB, 256, 0, stream>>>(Y2, Wc3, C3P, CP, NB);
  k_fc    <<<64, 256, 0, stream>>>(C3P, bc3, Wf, bfp, gf, bef, Wo, bo, out, NB);
}